// Round 2
// baseline (2156.813 us; speedup 1.0000x reference)
//
#include <hip/hip_runtime.h>
#include <hip/hip_bf16.h>

#define T_DIM 512
#define H_DIM 4096
#define F_DIM 14336
#define KSEG  8   // split-K for down GEMM: 14336/8 = 1792 = 28 iters of 64

typedef __attribute__((ext_vector_type(8))) short bf16x8;
typedef __attribute__((ext_vector_type(4))) float f32x4;

__device__ __forceinline__ unsigned short f2bf(float f) {
    union { float f; unsigned u; } v; v.f = f;
    unsigned r = v.u + 0x7fffu + ((v.u >> 16) & 1u);  // RNE
    return (unsigned short)(r >> 16);
}

// Zero d_out (harness poisons it with 0xAA; down_kernel accumulates via atomics).
__global__ __launch_bounds__(256) void zero_out(float4* __restrict__ out) {
    out[blockIdx.x * 256 + threadIdx.x] = make_float4(0.f, 0.f, 0.f, 0.f);
}

// X fp32 -> bf16 once (saves 3 VALU/elem x 112-fold re-staging in gate_up).
__global__ __launch_bounds__(256) void cvt_x(const float* __restrict__ X,
                                             unsigned short* __restrict__ Xb) {
    int i = (blockIdx.x * 256 + threadIdx.x) * 4;
    float4 v = *(const float4*)&X[i];
    ushort4 o;
    o.x = f2bf(v.x); o.y = f2bf(v.y); o.z = f2bf(v.z); o.w = f2bf(v.w);
    *(ushort4*)&Xb[i] = o;
}

// ---------------------------------------------------------------------------
// G = silu(X@W1^T) * (X@W3^T)  -> bf16 [T,F]
// 128x128 tile, BK=64(=GROUP). 4 waves; each wave owns 64x64 (4x4 frags) for
// BOTH W1 and W3 accumulators. Grid (T/128=4, F/128=112) = 448 blocks.
// LDS 55.3 KB -> 2 blocks/CU.
// ---------------------------------------------------------------------------
__global__ __launch_bounds__(256, 2)
void gate_up_kernel(const unsigned short* __restrict__ Xb,
                    const int* __restrict__ W1q, const float* __restrict__ sc1,
                    const float* __restrict__ zp1,
                    const int* __restrict__ W3q, const float* __restrict__ sc3,
                    const float* __restrict__ zp3,
                    unsigned short* __restrict__ G)
{
    constexpr int LK = 72;  // 144 B row stride: 16B-aligned (9x16B), +4 bank shift/row
    __shared__ unsigned short sX[128 * LK];
    __shared__ unsigned short sW1[128 * LK];
    __shared__ unsigned short sW3[128 * LK];

    const int t = threadIdx.x, wave = t >> 6, lane = t & 63;
    const int r = lane & 15, q = lane >> 4;
    const int wm = (wave & 1) * 64, wn = (wave >> 1) * 64;
    const int m0 = blockIdx.x * 128, n0 = blockIdx.y * 128;
    const int SG = H_DIM / 64;

    f32x4 acc1[4][4], acc3[4][4];
    #pragma unroll
    for (int a = 0; a < 4; ++a)
        #pragma unroll
        for (int b = 0; b < 4; ++b) {
            acc1[a][b] = (f32x4){0.f, 0.f, 0.f, 0.f};
            acc3[a][b] = (f32x4){0.f, 0.f, 0.f, 0.f};
        }

    for (int k0 = 0; k0 < H_DIM; k0 += 64) {
        const int gidx = k0 >> 6;

        // stage X tile 128x64 bf16 (pure copy, 4x16B per thread)
        #pragma unroll
        for (int i = 0; i < 4; ++i) {
            int p = t + 256 * i;
            int row = p >> 3, ch = p & 7;
            *(int4*)&sX[row * LK + ch * 8] =
                *(const int4*)&Xb[(size_t)(m0 + row) * H_DIM + k0 + ch * 8];
        }
        // stage W1/W3 tiles 128x64 int -> dequant bf16 (8 int4 per thread each)
        #pragma unroll
        for (int i = 0; i < 8; ++i) {
            int p = t + 256 * i;
            int row = p >> 4, c = (p & 15) * 4;
            int sidx = (n0 + row) * SG + gidx;

            float s = sc1[sidx];
            float nzs = -zp1[sidx] * s;
            int4 qv = *(const int4*)&W1q[(size_t)(n0 + row) * H_DIM + k0 + c];
            ushort4 o;
            o.x = f2bf(fmaf((float)qv.x, s, nzs)); o.y = f2bf(fmaf((float)qv.y, s, nzs));
            o.z = f2bf(fmaf((float)qv.z, s, nzs)); o.w = f2bf(fmaf((float)qv.w, s, nzs));
            *(ushort4*)&sW1[row * LK + c] = o;

            s = sc3[sidx];
            nzs = -zp3[sidx] * s;
            qv = *(const int4*)&W3q[(size_t)(n0 + row) * H_DIM + k0 + c];
            o.x = f2bf(fmaf((float)qv.x, s, nzs)); o.y = f2bf(fmaf((float)qv.y, s, nzs));
            o.z = f2bf(fmaf((float)qv.z, s, nzs)); o.w = f2bf(fmaf((float)qv.w, s, nzs));
            *(ushort4*)&sW3[row * LK + c] = o;
        }
        __syncthreads();

        #pragma unroll
        for (int kh = 0; kh < 2; ++kh) {
            const int kb = kh * 32 + q * 8;
            bf16x8 av[4], b1[4], b3[4];
            #pragma unroll
            for (int im = 0; im < 4; ++im)
                av[im] = *(const bf16x8*)&sX[(wm + im * 16 + r) * LK + kb];
            #pragma unroll
            for (int j = 0; j < 4; ++j) {
                b1[j] = *(const bf16x8*)&sW1[(wn + j * 16 + r) * LK + kb];
                b3[j] = *(const bf16x8*)&sW3[(wn + j * 16 + r) * LK + kb];
            }
            #pragma unroll
            for (int im = 0; im < 4; ++im)
                #pragma unroll
                for (int j = 0; j < 4; ++j) {
                    acc1[im][j] = __builtin_amdgcn_mfma_f32_16x16x32_bf16(av[im], b1[j], acc1[im][j], 0, 0, 0);
                    acc3[im][j] = __builtin_amdgcn_mfma_f32_16x16x32_bf16(av[im], b3[j], acc3[im][j], 0, 0, 0);
                }
        }
        __syncthreads();
    }

    #pragma unroll
    for (int im = 0; im < 4; ++im)
        #pragma unroll
        for (int j = 0; j < 4; ++j)
            #pragma unroll
            for (int reg = 0; reg < 4; ++reg) {
                int m = m0 + wm + im * 16 + q * 4 + reg;
                int f = n0 + wn + j * 16 + r;
                float g1 = acc1[im][j][reg];
                float g3 = acc3[im][j][reg];
                float val = g1 / (1.f + __expf(-g1)) * g3;
                G[(size_t)m * F_DIM + f] = f2bf(val);
            }
}

// ---------------------------------------------------------------------------
// out += G @ W2^T  (split-K). 128x128 tile, 4 waves x 64x64. KSEG=8 ->
// grid (4, 32, 8) = 1024 blocks. Epilogue: fp32 atomicAdd into zeroed d_out.
// LDS 36.9 KB.
// ---------------------------------------------------------------------------
__global__ __launch_bounds__(256, 2)
void down_kernel(const unsigned short* __restrict__ G,
                 const int* __restrict__ W2q, const float* __restrict__ sc2,
                 const float* __restrict__ zp2,
                 float* __restrict__ Out)
{
    constexpr int LK = 72;
    __shared__ unsigned short sA[128 * LK];
    __shared__ unsigned short sW[128 * LK];

    const int t = threadIdx.x, wave = t >> 6, lane = t & 63;
    const int r = lane & 15, q = lane >> 4;
    const int wm = (wave & 1) * 64, wn = (wave >> 1) * 64;
    const int m0 = blockIdx.x * 128, n0 = blockIdx.y * 128;
    const int kbeg = blockIdx.z * (F_DIM / KSEG);
    const int kend = kbeg + (F_DIM / KSEG);
    const int SG = F_DIM / 64;

    f32x4 acc[4][4];
    #pragma unroll
    for (int a = 0; a < 4; ++a)
        #pragma unroll
        for (int b = 0; b < 4; ++b) acc[a][b] = (f32x4){0.f, 0.f, 0.f, 0.f};

    for (int k0 = kbeg; k0 < kend; k0 += 64) {
        const int gidx = k0 >> 6;

        // stage A tile (G, bf16 copy)
        #pragma unroll
        for (int i = 0; i < 4; ++i) {
            int p = t + 256 * i;
            int row = p >> 3, ch = p & 7;
            *(int4*)&sA[row * LK + ch * 8] =
                *(const int4*)&G[(size_t)(m0 + row) * F_DIM + k0 + ch * 8];
        }
        // stage W2 tile: dequant
        #pragma unroll
        for (int i = 0; i < 8; ++i) {
            int p = t + 256 * i;
            int row = p >> 4, c = (p & 15) * 4;
            int sidx = (n0 + row) * SG + gidx;
            float s = sc2[sidx];
            float nzs = -zp2[sidx] * s;
            int4 qv = *(const int4*)&W2q[(size_t)(n0 + row) * F_DIM + k0 + c];
            ushort4 o;
            o.x = f2bf(fmaf((float)qv.x, s, nzs)); o.y = f2bf(fmaf((float)qv.y, s, nzs));
            o.z = f2bf(fmaf((float)qv.z, s, nzs)); o.w = f2bf(fmaf((float)qv.w, s, nzs));
            *(ushort4*)&sW[row * LK + c] = o;
        }
        __syncthreads();

        #pragma unroll
        for (int kh = 0; kh < 2; ++kh) {
            const int kb = kh * 32 + q * 8;
            bf16x8 av[4], bv[4];
            #pragma unroll
            for (int im = 0; im < 4; ++im)
                av[im] = *(const bf16x8*)&sA[(wm + im * 16 + r) * LK + kb];
            #pragma unroll
            for (int j = 0; j < 4; ++j)
                bv[j] = *(const bf16x8*)&sW[(wn + j * 16 + r) * LK + kb];
            #pragma unroll
            for (int im = 0; im < 4; ++im)
                #pragma unroll
                for (int j = 0; j < 4; ++j)
                    acc[im][j] = __builtin_amdgcn_mfma_f32_16x16x32_bf16(av[im], bv[j], acc[im][j], 0, 0, 0);
        }
        __syncthreads();
    }

    #pragma unroll
    for (int im = 0; im < 4; ++im)
        #pragma unroll
        for (int j = 0; j < 4; ++j)
            #pragma unroll
            for (int reg = 0; reg < 4; ++reg) {
                int m = m0 + wm + im * 16 + q * 4 + reg;
                int h = n0 + wn + j * 16 + r;
                atomicAdd(&Out[(size_t)m * H_DIM + h], acc[im][j][reg]);
            }
}

extern "C" void kernel_launch(void* const* d_in, const int* in_sizes, int n_in,
                              void* d_out, int out_size, void* d_ws, size_t ws_size,
                              hipStream_t stream) {
    const float* X   = (const float*)d_in[0];
    const int*   W1q = (const int*)d_in[1];
    const float* s1  = (const float*)d_in[2];
    const float* z1  = (const float*)d_in[3];
    const int*   W3q = (const int*)d_in[4];
    const float* s3  = (const float*)d_in[5];
    const float* z3  = (const float*)d_in[6];
    const int*   W2q = (const int*)d_in[7];
    const float* s2  = (const float*)d_in[8];
    const float* z2  = (const float*)d_in[9];
    float* Out = (float*)d_out;

    unsigned short* Xb = (unsigned short*)d_ws;                       // 4 MB
    unsigned short* G  = (unsigned short*)((char*)d_ws + (4 << 20));  // 14.7 MB

    zero_out<<<2048, 256, 0, stream>>>((float4*)Out);
    cvt_x<<<2048, 256, 0, stream>>>(X, Xb);
    gate_up_kernel<<<dim3(T_DIM / 128, F_DIM / 128), 256, 0, stream>>>(
        Xb, W1q, s1, z1, W3q, s3, z3, G);
    down_kernel<<<dim3(T_DIM / 128, H_DIM / 128, KSEG), 256, 0, stream>>>(
        G, W2q, s2, z2, Out);
}

// Round 3
// 1236.691 us; speedup vs baseline: 1.7440x; 1.7440x over previous
//
#include <hip/hip_runtime.h>
#include <hip/hip_bf16.h>

#define T_DIM 512
#define H_DIM 4096
#define F_DIM 14336
#define KSEG  8   // split-K segments for down GEMM (14336/8 = 1792 = 28 x 64)

typedef __attribute__((ext_vector_type(8))) short bf16x8;
typedef __attribute__((ext_vector_type(4))) float f32x4;

__device__ __forceinline__ unsigned short f2bf(float f) {
    union { float f; unsigned u; } v; v.f = f;
    unsigned r = v.u + 0x7fffu + ((v.u >> 16) & 1u);  // RNE
    return (unsigned short)(r >> 16);
}

// Zero d_out (harness poisons with 0xAA; down_kernel accumulates via atomics).
__global__ __launch_bounds__(256) void zero_out(float4* __restrict__ out) {
    out[blockIdx.x * 256 + threadIdx.x] = make_float4(0.f, 0.f, 0.f, 0.f);
}

// X fp32 -> bf16 once.
__global__ __launch_bounds__(256) void cvt_x(const float* __restrict__ X,
                                             unsigned short* __restrict__ Xb) {
    int i = (blockIdx.x * 256 + threadIdx.x) * 4;
    float4 v = *(const float4*)&X[i];
    ushort4 o;
    o.x = f2bf(v.x); o.y = f2bf(v.y); o.z = f2bf(v.z); o.w = f2bf(v.w);
    *(ushort4*)&Xb[i] = o;
}

// ---------------------------------------------------------------------------
// G = silu(X@W1^T) * (X@W3^T) -> bf16 [T,F]
// Tile M128 x N64 x K64(=GROUP). 4 waves: wave&1 = m-half, wave>>1 = matrix
// (0->W1, 1->W3). Each wave: 64x64 output, 4x4 frags, 32 MFMA/iter.
// Register prefetch of next K-tile overlaps fetch with dequant+MFMA.
// Epilogue: W3 waves dump acc to LDS; W1 waves do silu*mul and store G.
// Grid: flat 896, XCD-swizzled so the 4 m-siblings of an n-tile run
// concurrently on one XCD (weights stream through its L2 once).
// ---------------------------------------------------------------------------
__global__ __launch_bounds__(256, 2)
void gate_up_kernel(const unsigned short* __restrict__ Xb,
                    const int* __restrict__ W1q, const float* __restrict__ sc1,
                    const float* __restrict__ zp1,
                    const int* __restrict__ W3q, const float* __restrict__ sc3,
                    const float* __restrict__ zp3,
                    unsigned short* __restrict__ G)
{
    constexpr int LK = 72;  // bf16 elems/row: 144 B stride, 16B-aligned
    __shared__ __align__(16) char smem[(128 + 64 + 64) * LK * 2];  // 36864 B
    unsigned short* sX  = (unsigned short*)smem;
    unsigned short* sW1 = (unsigned short*)(smem + 128 * LK * 2);
    unsigned short* sW3 = (unsigned short*)(smem + 192 * LK * 2);
    float* sEx = (float*)smem;  // epilogue reuse: 128*65*4 = 33280 B

    const int t = threadIdx.x, wave = t >> 6, lane = t & 63;
    const int r = lane & 15, q = lane >> 4;
    const int mh  = (wave & 1) * 64;   // wave's m-offset in tile
    const int mat = wave >> 1;         // 0 -> W1, 1 -> W3

    // XCD swizzle: b%8 = XCD; within XCD, m-sibling index fastest.
    const int b = blockIdx.x;
    const int xcd = b & 7, lb = b >> 3;         // lb in [0,112)
    const int m0 = (lb & 3) * 128;
    const int n0 = (xcd * 28 + (lb >> 2)) * 64; // n-tile in [0,224)
    const int SG = H_DIM / 64;

    // staging coords
    const int xrow = t >> 3, xch = (t & 7) * 8;   // X: rows xrow+32i, 16B chunk
    const int wrow = t >> 4, wc = (t & 15) * 4;   // W: rows wrow+16i, 4 int32

    int4 pX[4], pW1[4], pW3[4];
    float pS1[4], pZ1[4], pS3[4], pZ3[4];

    // initial prefetch (k0 = 0)
    #pragma unroll
    for (int i = 0; i < 4; ++i)
        pX[i] = *(const int4*)&Xb[(size_t)(m0 + xrow + 32 * i) * H_DIM + xch];
    #pragma unroll
    for (int i = 0; i < 4; ++i) {
        int row = wrow + 16 * i;
        size_t off = (size_t)(n0 + row) * H_DIM + wc;
        pW1[i] = *(const int4*)&W1q[off];
        pW3[i] = *(const int4*)&W3q[off];
        int sidx = (n0 + row) * SG;
        pS1[i] = sc1[sidx]; pZ1[i] = zp1[sidx];
        pS3[i] = sc3[sidx]; pZ3[i] = zp3[sidx];
    }

    f32x4 acc[4][4];
    #pragma unroll
    for (int a = 0; a < 4; ++a)
        #pragma unroll
        for (int c = 0; c < 4; ++c) acc[a][c] = (f32x4){0.f, 0.f, 0.f, 0.f};

    for (int k0 = 0; k0 < H_DIM; k0 += 64) {
        // ---- consume prefetched regs: copy/dequant -> LDS ----
        #pragma unroll
        for (int i = 0; i < 4; ++i)
            *(int4*)&sX[(xrow + 32 * i) * LK + xch] = pX[i];
        #pragma unroll
        for (int i = 0; i < 4; ++i) {
            int row = wrow + 16 * i;
            float s = pS1[i], nzs = -pZ1[i] * s;
            int4 qv = pW1[i];
            ushort4 o;
            o.x = f2bf(fmaf((float)qv.x, s, nzs)); o.y = f2bf(fmaf((float)qv.y, s, nzs));
            o.z = f2bf(fmaf((float)qv.z, s, nzs)); o.w = f2bf(fmaf((float)qv.w, s, nzs));
            *(ushort4*)&sW1[row * LK + wc] = o;
            s = pS3[i]; nzs = -pZ3[i] * s;
            qv = pW3[i];
            o.x = f2bf(fmaf((float)qv.x, s, nzs)); o.y = f2bf(fmaf((float)qv.y, s, nzs));
            o.z = f2bf(fmaf((float)qv.z, s, nzs)); o.w = f2bf(fmaf((float)qv.w, s, nzs));
            *(ushort4*)&sW3[row * LK + wc] = o;
        }
        // ---- issue next tile's loads (in flight across barrier + MFMA) ----
        int kn = k0 + 64;
        if (kn < H_DIM) {
            int gidx = kn >> 6;
            #pragma unroll
            for (int i = 0; i < 4; ++i)
                pX[i] = *(const int4*)&Xb[(size_t)(m0 + xrow + 32 * i) * H_DIM + kn + xch];
            #pragma unroll
            for (int i = 0; i < 4; ++i) {
                int row = wrow + 16 * i;
                size_t off = (size_t)(n0 + row) * H_DIM + kn + wc;
                pW1[i] = *(const int4*)&W1q[off];
                pW3[i] = *(const int4*)&W3q[off];
                int sidx = (n0 + row) * SG + gidx;
                pS1[i] = sc1[sidx]; pZ1[i] = zp1[sidx];
                pS3[i] = sc3[sidx]; pZ3[i] = zp3[sidx];
            }
        }
        __syncthreads();

        const unsigned short* sB = mat ? sW3 : sW1;
        #pragma unroll
        for (int kh = 0; kh < 2; ++kh) {
            const int kb = kh * 32 + q * 8;
            bf16x8 av[4], bv[4];
            #pragma unroll
            for (int im = 0; im < 4; ++im)
                av[im] = *(const bf16x8*)&sX[(mh + im * 16 + r) * LK + kb];
            #pragma unroll
            for (int j = 0; j < 4; ++j)
                bv[j] = *(const bf16x8*)&sB[(j * 16 + r) * LK + kb];
            #pragma unroll
            for (int im = 0; im < 4; ++im)
                #pragma unroll
                for (int j = 0; j < 4; ++j)
                    acc[im][j] = __builtin_amdgcn_mfma_f32_16x16x32_bf16(av[im], bv[j], acc[im][j], 0, 0, 0);
        }
        __syncthreads();
    }

    // ---- epilogue: exchange g3 via LDS, then silu(g1)*g3 ----
    if (mat == 1) {
        #pragma unroll
        for (int im = 0; im < 4; ++im)
            #pragma unroll
            for (int j = 0; j < 4; ++j)
                #pragma unroll
                for (int reg = 0; reg < 4; ++reg)
                    sEx[(mh + im * 16 + q * 4 + reg) * 65 + j * 16 + r] = acc[im][j][reg];
    }
    __syncthreads();
    if (mat == 0) {
        #pragma unroll
        for (int im = 0; im < 4; ++im)
            #pragma unroll
            for (int j = 0; j < 4; ++j)
                #pragma unroll
                for (int reg = 0; reg < 4; ++reg) {
                    int ml = mh + im * 16 + q * 4 + reg;
                    int nl = j * 16 + r;
                    float g1 = acc[im][j][reg];
                    float g3 = sEx[ml * 65 + nl];
                    float val = g1 / (1.f + __expf(-g1)) * g3;
                    G[(size_t)(m0 + ml) * F_DIM + n0 + nl] = f2bf(val);
                }
    }
}

// ---------------------------------------------------------------------------
// out += G @ W2^T (split-K, fp32 atomics). Tile M128 x N128 x K64, 4 waves
// x 64x64. Same register prefetch + XCD swizzle (m-siblings share W2 tile).
// Grid: flat 1024 = 4(m) x 32(n) x 8(kseg).
// ---------------------------------------------------------------------------
__global__ __launch_bounds__(256, 2)
void down_kernel(const unsigned short* __restrict__ G,
                 const int* __restrict__ W2q, const float* __restrict__ sc2,
                 const float* __restrict__ zp2,
                 float* __restrict__ Out)
{
    constexpr int LK = 72;
    __shared__ __align__(16) char smem[(128 + 128) * LK * 2];  // 36864 B
    unsigned short* sA = (unsigned short*)smem;
    unsigned short* sW = (unsigned short*)(smem + 128 * LK * 2);

    const int t = threadIdx.x, wave = t >> 6, lane = t & 63;
    const int r = lane & 15, q = lane >> 4;
    const int wm = (wave & 1) * 64, wn = (wave >> 1) * 64;

    const int b = blockIdx.x;
    const int xcd = b & 7, lb = b >> 3;          // lb in [0,128)
    const int m0 = (lb & 3) * 128;
    const int pair = xcd * 32 + (lb >> 2);       // [0,256)
    const int n0 = (pair >> 3) * 128;            // 32 n-tiles
    const int kbeg = (pair & 7) * (F_DIM / KSEG);
    const int kend = kbeg + (F_DIM / KSEG);
    const int SG = F_DIM / 64;

    const int arow = t >> 3, ach = (t & 7) * 8;
    const int wrow = t >> 4, wc = (t & 15) * 4;

    int4 pA[4], pW[8];
    float pS[8], pZ[8];

    #pragma unroll
    for (int i = 0; i < 4; ++i)
        pA[i] = *(const int4*)&G[(size_t)(m0 + arow + 32 * i) * F_DIM + kbeg + ach];
    #pragma unroll
    for (int i = 0; i < 8; ++i) {
        int row = wrow + 16 * i;
        pW[i] = *(const int4*)&W2q[(size_t)(n0 + row) * F_DIM + kbeg + wc];
        int sidx = (n0 + row) * SG + (kbeg >> 6);
        pS[i] = sc2[sidx]; pZ[i] = zp2[sidx];
    }

    f32x4 acc[4][4];
    #pragma unroll
    for (int a = 0; a < 4; ++a)
        #pragma unroll
        for (int c = 0; c < 4; ++c) acc[a][c] = (f32x4){0.f, 0.f, 0.f, 0.f};

    for (int k0 = kbeg; k0 < kend; k0 += 64) {
        #pragma unroll
        for (int i = 0; i < 4; ++i)
            *(int4*)&sA[(arow + 32 * i) * LK + ach] = pA[i];
        #pragma unroll
        for (int i = 0; i < 8; ++i) {
            int row = wrow + 16 * i;
            float s = pS[i], nzs = -pZ[i] * s;
            int4 qv = pW[i];
            ushort4 o;
            o.x = f2bf(fmaf((float)qv.x, s, nzs)); o.y = f2bf(fmaf((float)qv.y, s, nzs));
            o.z = f2bf(fmaf((float)qv.z, s, nzs)); o.w = f2bf(fmaf((float)qv.w, s, nzs));
            *(ushort4*)&sW[row * LK + wc] = o;
        }
        int kn = k0 + 64;
        if (kn < kend) {
            int gidx = kn >> 6;
            #pragma unroll
            for (int i = 0; i < 4; ++i)
                pA[i] = *(const int4*)&G[(size_t)(m0 + arow + 32 * i) * F_DIM + kn + ach];
            #pragma unroll
            for (int i = 0; i < 8; ++i) {
                int row = wrow + 16 * i;
                pW[i] = *(const int4*)&W2q[(size_t)(n0 + row) * F_DIM + kn + wc];
                int sidx = (n0 + row) * SG + gidx;
                pS[i] = sc2[sidx]; pZ[i] = zp2[sidx];
            }
        }
        __syncthreads();

        #pragma unroll
        for (int kh = 0; kh < 2; ++kh) {
            const int kb = kh * 32 + q * 8;
            bf16x8 av[4], bv[4];
            #pragma unroll
            for (int im = 0; im < 4; ++im)
                av[im] = *(const bf16x8*)&sA[(wm + im * 16 + r) * LK + kb];
            #pragma unroll
            for (int j = 0; j < 4; ++j)
                bv[j] = *(const bf16x8*)&sW[(wn + j * 16 + r) * LK + kb];
            #pragma unroll
            for (int im = 0; im < 4; ++im)
                #pragma unroll
                for (int j = 0; j < 4; ++j)
                    acc[im][j] = __builtin_amdgcn_mfma_f32_16x16x32_bf16(av[im], bv[j], acc[im][j], 0, 0, 0);
        }
        __syncthreads();
    }

    #pragma unroll
    for (int im = 0; im < 4; ++im)
        #pragma unroll
        for (int j = 0; j < 4; ++j)
            #pragma unroll
            for (int reg = 0; reg < 4; ++reg) {
                int m = m0 + wm + im * 16 + q * 4 + reg;
                int h = n0 + wn + j * 16 + r;
                atomicAdd(&Out[(size_t)m * H_DIM + h], acc[im][j][reg]);
            }
}

extern "C" void kernel_launch(void* const* d_in, const int* in_sizes, int n_in,
                              void* d_out, int out_size, void* d_ws, size_t ws_size,
                              hipStream_t stream) {
    const float* X   = (const float*)d_in[0];
    const int*   W1q = (const int*)d_in[1];
    const float* s1  = (const float*)d_in[2];
    const float* z1  = (const float*)d_in[3];
    const int*   W3q = (const int*)d_in[4];
    const float* s3  = (const float*)d_in[5];
    const float* z3  = (const float*)d_in[6];
    const int*   W2q = (const int*)d_in[7];
    const float* s2  = (const float*)d_in[8];
    const float* z2  = (const float*)d_in[9];
    float* Out = (float*)d_out;

    unsigned short* Xb = (unsigned short*)d_ws;                       // 4 MB
    unsigned short* G  = (unsigned short*)((char*)d_ws + (4 << 20));  // 14.7 MB

    zero_out<<<2048, 256, 0, stream>>>((float4*)Out);
    cvt_x<<<2048, 256, 0, stream>>>(X, Xb);
    gate_up_kernel<<<896, 256, 0, stream>>>(Xb, W1q, s1, z1, W3q, s3, z3, G);
    down_kernel<<<1024, 256, 0, stream>>>(G, W2q, s2, z2, Out);
}

// Round 4
// 912.919 us; speedup vs baseline: 2.3625x; 1.3547x over previous
//
#include <hip/hip_runtime.h>
#include <hip/hip_bf16.h>

#define T_DIM 512
#define H_DIM 4096
#define F_DIM 14336
#define KSEG  8   // split-K segments for down GEMM (14336/8 = 1792 = 28 x 64)

typedef __attribute__((ext_vector_type(8))) short bf16x8;
typedef __attribute__((ext_vector_type(4))) float f32x4;

__device__ __forceinline__ unsigned short f2bf(float f) {
    union { float f; unsigned u; } v; v.f = f;
    unsigned r = v.u + 0x7fffu + ((v.u >> 16) & 1u);  // RNE
    return (unsigned short)(r >> 16);
}

// Zero d_out (harness poisons with 0xAA; down_kernel accumulates via atomics).
__global__ __launch_bounds__(256) void zero_out(float4* __restrict__ out) {
    out[blockIdx.x * 256 + threadIdx.x] = make_float4(0.f, 0.f, 0.f, 0.f);
}

// X fp32 -> bf16 once.
__global__ __launch_bounds__(256) void cvt_x(const float* __restrict__ X,
                                             unsigned short* __restrict__ Xb) {
    int i = (blockIdx.x * 256 + threadIdx.x) * 4;
    float4 v = *(const float4*)&X[i];
    ushort4 o;
    o.x = f2bf(v.x); o.y = f2bf(v.y); o.z = f2bf(v.z); o.w = f2bf(v.w);
    *(ushort4*)&Xb[i] = o;
}

// ---------------------------------------------------------------------------
// G = silu(X@W1^T) * (X@W3^T) -> bf16 [T,F]
// Tile M128 x N64 x K64(=GROUP). 4 waves: wave&1 = m-half, wave>>1 = matrix.
// ONLY the weight streams (HBM-latency) are register-prefetched: 8 int4 =
// 32 VGPRs live across the barrier. X and scales are L2/L3-resident and
// loaded synchronously (spill avoidance — R3 spilled 578 MB of scratch).
// Grid: flat 896, XCD-swizzled (4 m-siblings concurrent per XCD).
// ---------------------------------------------------------------------------
__global__ __launch_bounds__(256, 2)
void gate_up_kernel(const unsigned short* __restrict__ Xb,
                    const int* __restrict__ W1q, const float* __restrict__ sc1,
                    const float* __restrict__ zp1,
                    const int* __restrict__ W3q, const float* __restrict__ sc3,
                    const float* __restrict__ zp3,
                    unsigned short* __restrict__ G)
{
    constexpr int LK = 72;  // 144 B row stride, 16B-aligned, +4 bank shift/row
    __shared__ __align__(16) char smem[(128 + 64 + 64) * LK * 2];  // 36864 B
    unsigned short* sX  = (unsigned short*)smem;
    unsigned short* sW1 = (unsigned short*)(smem + 128 * LK * 2);
    unsigned short* sW3 = (unsigned short*)(smem + 192 * LK * 2);
    float* sEx = (float*)smem;  // epilogue reuse: 128*65*4 = 33280 B

    const int t = threadIdx.x, wave = t >> 6, lane = t & 63;
    const int r = lane & 15, q = lane >> 4;
    const int mh  = (wave & 1) * 64;   // wave's m-offset in tile
    const int mat = wave >> 1;         // 0 -> W1, 1 -> W3

    const int b = blockIdx.x;
    const int xcd = b & 7, lb = b >> 3;         // lb in [0,112)
    const int m0 = (lb & 3) * 128;
    const int n0 = (xcd * 28 + (lb >> 2)) * 64; // n-tile in [0,224)
    const int SG = H_DIM / 64;

    const int xrow = t >> 3, xch = (t & 7) * 8;   // X: rows xrow+32i, 16B chunk
    const int wrow = t >> 4, wc = (t & 15) * 4;   // W: rows wrow+16i, 4 int32

    // weight-only prefetch (32 VGPRs live across barriers)
    int4 pW1[4], pW3[4];
    #pragma unroll
    for (int i = 0; i < 4; ++i) {
        size_t off = (size_t)(n0 + wrow + 16 * i) * H_DIM + wc;
        pW1[i] = *(const int4*)&W1q[off];
        pW3[i] = *(const int4*)&W3q[off];
    }

    f32x4 acc[4][4];
    #pragma unroll
    for (int a = 0; a < 4; ++a)
        #pragma unroll
        for (int c = 0; c < 4; ++c) acc[a][c] = (f32x4){0.f, 0.f, 0.f, 0.f};

    for (int k0 = 0; k0 < H_DIM; k0 += 64) {
        const int gidx = k0 >> 6;

        // ---- X tile: sync copy (L2/L3-resident, 4 MB total) ----
        #pragma unroll
        for (int i = 0; i < 4; ++i) {
            int4 xv = *(const int4*)&Xb[(size_t)(m0 + xrow + 32 * i) * H_DIM + k0 + xch];
            *(int4*)&sX[(xrow + 32 * i) * LK + xch] = xv;
        }
        // ---- dequant prefetched weights -> LDS (scales loaded sync, L2) ----
        #pragma unroll
        for (int i = 0; i < 4; ++i) {
            int row = wrow + 16 * i;
            int sidx = (n0 + row) * SG + gidx;
            float s = sc1[sidx], nzs = -zp1[sidx] * s;
            int4 qv = pW1[i];
            ushort4 o;
            o.x = f2bf(fmaf((float)qv.x, s, nzs)); o.y = f2bf(fmaf((float)qv.y, s, nzs));
            o.z = f2bf(fmaf((float)qv.z, s, nzs)); o.w = f2bf(fmaf((float)qv.w, s, nzs));
            *(ushort4*)&sW1[row * LK + wc] = o;
            s = sc3[sidx]; nzs = -zp3[sidx] * s;
            qv = pW3[i];
            o.x = f2bf(fmaf((float)qv.x, s, nzs)); o.y = f2bf(fmaf((float)qv.y, s, nzs));
            o.z = f2bf(fmaf((float)qv.z, s, nzs)); o.w = f2bf(fmaf((float)qv.w, s, nzs));
            *(ushort4*)&sW3[row * LK + wc] = o;
        }
        // ---- issue next K-tile's weight loads (stay in flight over MFMA) ----
        int kn = k0 + 64;
        if (kn < H_DIM) {
            #pragma unroll
            for (int i = 0; i < 4; ++i) {
                size_t off = (size_t)(n0 + wrow + 16 * i) * H_DIM + kn + wc;
                pW1[i] = *(const int4*)&W1q[off];
                pW3[i] = *(const int4*)&W3q[off];
            }
        }
        __syncthreads();

        const unsigned short* sB = mat ? sW3 : sW1;
        #pragma unroll
        for (int kh = 0; kh < 2; ++kh) {
            const int kb = kh * 32 + q * 8;
            bf16x8 av[4], bv[4];
            #pragma unroll
            for (int im = 0; im < 4; ++im)
                av[im] = *(const bf16x8*)&sX[(mh + im * 16 + r) * LK + kb];
            #pragma unroll
            for (int j = 0; j < 4; ++j)
                bv[j] = *(const bf16x8*)&sB[(j * 16 + r) * LK + kb];
            #pragma unroll
            for (int im = 0; im < 4; ++im)
                #pragma unroll
                for (int j = 0; j < 4; ++j)
                    acc[im][j] = __builtin_amdgcn_mfma_f32_16x16x32_bf16(av[im], bv[j], acc[im][j], 0, 0, 0);
        }
        __syncthreads();
    }

    // ---- epilogue: exchange g3 via LDS, then silu(g1)*g3 ----
    if (mat == 1) {
        #pragma unroll
        for (int im = 0; im < 4; ++im)
            #pragma unroll
            for (int j = 0; j < 4; ++j)
                #pragma unroll
                for (int reg = 0; reg < 4; ++reg)
                    sEx[(mh + im * 16 + q * 4 + reg) * 65 + j * 16 + r] = acc[im][j][reg];
    }
    __syncthreads();
    if (mat == 0) {
        #pragma unroll
        for (int im = 0; im < 4; ++im)
            #pragma unroll
            for (int j = 0; j < 4; ++j)
                #pragma unroll
                for (int reg = 0; reg < 4; ++reg) {
                    int ml = mh + im * 16 + q * 4 + reg;
                    int nl = j * 16 + r;
                    float g1 = acc[im][j][reg];
                    float g3 = sEx[ml * 65 + nl];
                    float val = g1 / (1.f + __expf(-g1)) * g3;
                    G[(size_t)(m0 + ml) * F_DIM + n0 + nl] = f2bf(val);
                }
    }
}

// ---------------------------------------------------------------------------
// out += G @ W2^T (split-K, fp32 atomics). Tile M128 x N128 x K64, 4 waves
// x 64x64. Weight-only register prefetch; G + scales loaded sync (L2/L3).
// Grid: flat 1024 = 4(m) x 32(n) x 8(kseg), XCD-swizzled.
// ---------------------------------------------------------------------------
__global__ __launch_bounds__(256, 2)
void down_kernel(const unsigned short* __restrict__ G,
                 const int* __restrict__ W2q, const float* __restrict__ sc2,
                 const float* __restrict__ zp2,
                 float* __restrict__ Out)
{
    constexpr int LK = 72;
    __shared__ __align__(16) char smem[(128 + 128) * LK * 2];  // 36864 B
    unsigned short* sA = (unsigned short*)smem;
    unsigned short* sW = (unsigned short*)(smem + 128 * LK * 2);

    const int t = threadIdx.x, wave = t >> 6, lane = t & 63;
    const int r = lane & 15, q = lane >> 4;
    const int wm = (wave & 1) * 64, wn = (wave >> 1) * 64;

    const int b = blockIdx.x;
    const int xcd = b & 7, lb = b >> 3;          // lb in [0,128)
    const int m0 = (lb & 3) * 128;
    const int pair = xcd * 32 + (lb >> 2);       // [0,256)
    const int n0 = (pair >> 3) * 128;            // 32 n-tiles
    const int kbeg = (pair & 7) * (F_DIM / KSEG);
    const int kend = kbeg + (F_DIM / KSEG);
    const int SG = F_DIM / 64;

    const int arow = t >> 3, ach = (t & 7) * 8;
    const int wrow = t >> 4, wc = (t & 15) * 4;

    // weight-only prefetch (32 VGPRs)
    int4 pW[8];
    #pragma unroll
    for (int i = 0; i < 8; ++i)
        pW[i] = *(const int4*)&W2q[(size_t)(n0 + wrow + 16 * i) * F_DIM + kbeg + wc];

    f32x4 acc[4][4];
    #pragma unroll
    for (int a = 0; a < 4; ++a)
        #pragma unroll
        for (int c = 0; c < 4; ++c) acc[a][c] = (f32x4){0.f, 0.f, 0.f, 0.f};

    for (int k0 = kbeg; k0 < kend; k0 += 64) {
        const int gidx = k0 >> 6;

        // ---- A tile (G bf16): sync copy (L3-resident, 14.7 MB) ----
        #pragma unroll
        for (int i = 0; i < 4; ++i) {
            int4 gv = *(const int4*)&G[(size_t)(m0 + arow + 32 * i) * F_DIM + k0 + ach];
            *(int4*)&sA[(arow + 32 * i) * LK + ach] = gv;
        }
        // ---- dequant prefetched W2 -> LDS ----
        #pragma unroll
        for (int i = 0; i < 8; ++i) {
            int row = wrow + 16 * i;
            int sidx = (n0 + row) * SG + gidx;
            float s = sc2[sidx], nzs = -zp2[sidx] * s;
            int4 qv = pW[i];
            ushort4 o;
            o.x = f2bf(fmaf((float)qv.x, s, nzs)); o.y = f2bf(fmaf((float)qv.y, s, nzs));
            o.z = f2bf(fmaf((float)qv.z, s, nzs)); o.w = f2bf(fmaf((float)qv.w, s, nzs));
            *(ushort4*)&sW[row * LK + wc] = o;
        }
        // ---- issue next K-tile weight loads ----
        int kn = k0 + 64;
        if (kn < kend) {
            #pragma unroll
            for (int i = 0; i < 8; ++i)
                pW[i] = *(const int4*)&W2q[(size_t)(n0 + wrow + 16 * i) * F_DIM + kn + wc];
        }
        __syncthreads();

        #pragma unroll
        for (int kh = 0; kh < 2; ++kh) {
            const int kb = kh * 32 + q * 8;
            bf16x8 av[4], bv[4];
            #pragma unroll
            for (int im = 0; im < 4; ++im)
                av[im] = *(const bf16x8*)&sA[(wm + im * 16 + r) * LK + kb];
            #pragma unroll
            for (int j = 0; j < 4; ++j)
                bv[j] = *(const bf16x8*)&sW[(wn + j * 16 + r) * LK + kb];
            #pragma unroll
            for (int im = 0; im < 4; ++im)
                #pragma unroll
                for (int j = 0; j < 4; ++j)
                    acc[im][j] = __builtin_amdgcn_mfma_f32_16x16x32_bf16(av[im], bv[j], acc[im][j], 0, 0, 0);
        }
        __syncthreads();
    }

    #pragma unroll
    for (int im = 0; im < 4; ++im)
        #pragma unroll
        for (int j = 0; j < 4; ++j)
            #pragma unroll
            for (int reg = 0; reg < 4; ++reg) {
                int m = m0 + wm + im * 16 + q * 4 + reg;
                int h = n0 + wn + j * 16 + r;
                atomicAdd(&Out[(size_t)m * H_DIM + h], acc[im][j][reg]);
            }
}

extern "C" void kernel_launch(void* const* d_in, const int* in_sizes, int n_in,
                              void* d_out, int out_size, void* d_ws, size_t ws_size,
                              hipStream_t stream) {
    const float* X   = (const float*)d_in[0];
    const int*   W1q = (const int*)d_in[1];
    const float* s1  = (const float*)d_in[2];
    const float* z1  = (const float*)d_in[3];
    const int*   W3q = (const int*)d_in[4];
    const float* s3  = (const float*)d_in[5];
    const float* z3  = (const float*)d_in[6];
    const int*   W2q = (const int*)d_in[7];
    const float* s2  = (const float*)d_in[8];
    const float* z2  = (const float*)d_in[9];
    float* Out = (float*)d_out;

    unsigned short* Xb = (unsigned short*)d_ws;                       // 4 MB
    unsigned short* G  = (unsigned short*)((char*)d_ws + (4 << 20));  // 14.7 MB

    zero_out<<<2048, 256, 0, stream>>>((float4*)Out);
    cvt_x<<<2048, 256, 0, stream>>>(X, Xb);
    gate_up_kernel<<<896, 256, 0, stream>>>(Xb, W1q, s1, z1, W3q, s3, z3, G);
    down_kernel<<<1024, 256, 0, stream>>>(G, W2q, s2, z2, Out);
}